// Round 2
// baseline (234.376 us; speedup 1.0000x reference)
//
#include <hip/hip_runtime.h>
#include <math.h>

// ---------------------------------------------------------------------------
// GMM log-likelihood, N=2M x D=16, K=32, out = mean_n logsumexp_k loglik[n,k]
//
// loglik[n,k] = sum_{ij} (-0.5 P_ij) x_i x_j + (P mu)_i x_i + c_k  (log2 dom.)
// LINEAR in phi(x) = [ x_i*x_j (256), x_i (16), 1 ] -> 18 K16-chunks of one
// chained mfma_f32_32x32x16_f16 (M=32 = all comps; c_k folded in as chunk 17).
// C layout (HW-verified): col=lane&31 (point), row=(reg&3)+8*(reg>>2)+4*(lane>>5).
// Lane pair (l, l^32) holds all 32 comps of a point; combined via
// v_permlane32_swap (VALU-only; ds shuffles cost ~62 cyc each, R2).
//
// R8: R7 (1-tile/iter, (256,3)) was a no-op vs R6 -> either main is already
// near the 20.3 us HBM floor (slack = launch overhead), or the 1-iteration
// prefetch distance still stalls every wave (3 stalling waves instead of 2).
// This round: (1) depth-2 pipeline with two NAMED register sets (rule #20:
// no runtime-indexed arrays) -> issue-to-use = 2 iters (~700 cyc covered);
// ~152 VGPR, still under the 168 cap of (256,3). (2) reduce_kernel fused
// into main via threadfence-reduction ticket (counter zeroed by setup each
// launch -> graph-replay safe; last block runs the IDENTICAL deterministic
// tree -> bitwise-equal result). Separable predictions: pipeline helps ->
// ~182 us; only fusion helps -> ~196 us (then we're at the roofline).
// ---------------------------------------------------------------------------

#define LOG_2PI 1.8378770664093453f
#define INV_LN2 1.4426950408889634f
#define LN2_D   0.6931471805599453

typedef float    float4v __attribute__((ext_vector_type(4)));
typedef float    f32x16  __attribute__((ext_vector_type(16)));
typedef _Float16 f16x8   __attribute__((ext_vector_type(8)));
typedef _Float16 f16x2   __attribute__((ext_vector_type(2)));

union H8 { f16x8 h8; f16x2 h2[4]; };

#if __has_builtin(__builtin_amdgcn_exp2f)
#define EXP2F(x) __builtin_amdgcn_exp2f(x)
#else
#define EXP2F(x) exp2f(x)
#endif
#if __has_builtin(__builtin_amdgcn_logf)
#define LOG2F(x) __builtin_amdgcn_logf(x)
#else
#define LOG2F(x) log2f(x)
#endif

static __device__ __forceinline__ f16x2 pk2(float a, float b) {
#if __has_builtin(__builtin_amdgcn_cvt_pkrtz)
  return __builtin_bit_cast(f16x2, __builtin_amdgcn_cvt_pkrtz(a, b));
#else
  f16x2 r; r[0] = (_Float16)a; r[1] = (_Float16)b; return r;
#endif
}

// value of x in partner lane (lane ^ 32), VALU-only on gfx950
static __device__ __forceinline__ float partner32(float x, bool lo) {
#if __has_builtin(__builtin_amdgcn_permlane32_swap)
  typedef unsigned u32x2 __attribute__((ext_vector_type(2)));
  unsigned u = __builtin_bit_cast(unsigned, x);
  u32x2 r = __builtin_amdgcn_permlane32_swap(u, u, false, false);
  return __builtin_bit_cast(float, lo ? r[1] : r[0]);
#else
  return __shfl_xor(x, 32, 64);
#endif
}

// dword select (works for f16x2 payloads)
static __device__ __forceinline__ f16x2 sel2(bool c, f16x2 a, f16x2 b) {
  unsigned ua = __builtin_bit_cast(unsigned, a);
  unsigned ub = __builtin_bit_cast(unsigned, b);
  return __builtin_bit_cast(f16x2, c ? ua : ub);
}

// ---------------------------------------------------------------------------
// Setup: per component k: cov = A A^T, Cholesky L, Linv, P = Linv^T Linv.
// W in 32x32x16 A-frag order: lane l holds A[m=l&31][k16 = 8*(l>>5)+v],
// chunk c covers feature k = 16c + 8h + v.
// chunks 0..15: (i,j)=(c, 8h+v) -> -0.5/ln2 * P[i][j]
// chunk 16: linear, feature i=8h+v -> (P mu)_i / ln2
// chunk 17: constant, slot (h=0,v=0) -> c2[m]; all other slots 0
// Also zeroes the main-kernel's ticket counter each launch (graph replay).
// ---------------------------------------------------------------------------
__global__ void setup_kernel(const float* __restrict__ means,
                             const float* __restrict__ cov_parts,
                             const float* __restrict__ log_weights,
                             _Float16* __restrict__ W,
                             unsigned* __restrict__ counter)
{
  const int k = blockIdx.x;
  const int i = threadIdx.x;

  if (k == 0 && i == 0) counter[0] = 0u;

  __shared__ float sA[16][17];
  __shared__ float sC[16][17];
  __shared__ float sMu[16];
  __shared__ float sR[16];

  if (i < 16) {
    #pragma unroll
    for (int j = 0; j < 16; ++j) sA[i][j] = cov_parts[(k*16 + i)*16 + j];
    sMu[i] = means[k*16 + i];
  }
  __syncthreads();

  if (i < 16) {
    #pragma unroll
    for (int j = 0; j < 16; ++j) {
      float acc = 0.f;
      #pragma unroll
      for (int l = 0; l < 16; ++l) acc += sA[i][l] * sA[j][l];
      sC[i][j] = acc;
    }
  }
  __syncthreads();

  for (int j = 0; j < 16; ++j) {
    if (i == j) {
      float d = sC[j][j];
      for (int l = 0; l < j; ++l) d -= sC[j][l]*sC[j][l];
      sC[j][j] = sqrtf(d);
    }
    __syncthreads();
    if (i < 16 && i > j) {
      float a = sC[i][j];
      for (int l = 0; l < j; ++l) a -= sC[i][l]*sC[j][l];
      sC[i][j] = a / sC[j][j];
    }
    __syncthreads();
  }

  if (i < 16) {
    float y[16];
    #pragma unroll
    for (int r = 0; r < 16; ++r) {
      float a = (r == i) ? 1.f : 0.f;
      #pragma unroll
      for (int l = 0; l < r; ++l) a -= sC[r][l] * y[l];
      y[r] = a / sC[r][r];
    }
    #pragma unroll
    for (int r = 0; r < 16; ++r) sA[r][i] = y[r];
  }
  __syncthreads();

  if (i < 16) {
    float p[16];
    #pragma unroll
    for (int j = 0; j < 16; ++j) {
      float acc = 0.f;
      #pragma unroll
      for (int l = 0; l < 16; ++l) acc += sA[l][i] * sA[l][j];
      p[j] = acc;
    }
    float ri = 0.f;
    #pragma unroll
    for (int j = 0; j < 16; ++j) ri += p[j] * sMu[j];
    sR[i] = ri;

    #pragma unroll
    for (int j = 0; j < 16; ++j) {
      W[(size_t)(i*64 + (k + 32*(j >> 3)))*8 + (j & 7)] =
          (_Float16)(-0.5f * INV_LN2 * p[j]);
    }
    W[(size_t)(16*64 + (k + 32*(i >> 3)))*8 + (i & 7)] =
        (_Float16)(INV_LN2 * ri);
  }
  __syncthreads();

  if (i == 0) {
    float logdet = 0.f;
    #pragma unroll
    for (int j = 0; j < 16; ++j) logdet += __logf(sC[j][j]);
    float mupmu = 0.f;
    #pragma unroll
    for (int j = 0; j < 16; ++j) mupmu += sMu[j] * sR[j];
    float lw = log_weights[k];
    float c2v = INV_LN2 * (-0.5f*(mupmu + 16.f*LOG_2PI) - logdet + lw*lw);
    #pragma unroll
    for (int v = 0; v < 8; ++v) {
      W[(size_t)(17*64 + k)*8 + v]      = (v == 0) ? (_Float16)c2v : (_Float16)0.f;
      W[(size_t)(17*64 + k + 32)*8 + v] = (_Float16)0.f;
    }
  }
}

// ---------------------------------------------------------------------------
__global__ __launch_bounds__(256, 3) void main_kernel(
    const float* __restrict__ data,
    const _Float16* __restrict__ W,
    float* __restrict__ partials,
    unsigned* __restrict__ counter,
    float* __restrict__ out,
    double scale,
    int ntiles)
{
  const int lane = threadIdx.x & 63;
  const int n32  = lane & 31;
  const bool lo  = lane < 32;
  const int gwave  = (int)((blockIdx.x * blockDim.x + threadIdx.x) >> 6);
  const int nwaves = (int)((gridDim.x * blockDim.x) >> 6);

  // W fragments resident in registers for the whole kernel (72 regs)
  f16x8 Wf[18];
  #pragma unroll
  for (int c = 0; c < 18; ++c)
    Wf[c] = *(const f16x8*)(W + (size_t)(c*64 + lane)*8);

  // constant B fragment for the c2 chunk: slot (h=0,v=0) = 1
  H8 bC;
  #pragma unroll
  for (int j = 0; j < 4; ++j) bC.h2[j] = pk2(0.f, 0.f);
  if (lo) bC.h2[0] = pk2(1.f, 0.f);

  float accsum = 0.f;

  // tile t covers points [t*32, t*32+32); lane pair (l, l^32) share point n32
  const char* ptrA = (const char*)data + ((size_t)gwave*2048 + (size_t)n32*64);
  const char* ptrB = ptrA + (size_t)nwaves*2048;
  const size_t step2 = (size_t)nwaves * 4096;   // advance by 2 iterations

  // two NAMED prefetch register sets (depth-2 pipeline, rule #20: no
  // runtime-indexed arrays)
  float4v pA0, pA1, pA2, pA3, pB0, pB1, pB2, pB3;
  if (gwave < ntiles) {
    pA0 = *(const float4v*)(ptrA);      pA1 = *(const float4v*)(ptrA + 16);
    pA2 = *(const float4v*)(ptrA + 32); pA3 = *(const float4v*)(ptrA + 48);
  }
  if (gwave + nwaves < ntiles) {
    pB0 = *(const float4v*)(ptrB);      pB1 = *(const float4v*)(ptrB + 16);
    pB2 = *(const float4v*)(ptrB + 32); pB3 = *(const float4v*)(ptrB + 48);
  }

  // processes tile t held in (q0..q3); prefetches tile t+2*nwaves into the
  // same set (consumed two iterations later)
  auto body = [&](float4v& q0, float4v& q1, float4v& q2, float4v& q3,
                  const char*& qptr, int t) {
    // convert to f16 pairs: xh[q] = (x[2q], x[2q+1])
    f16x2 xh[8];
    xh[0] = pk2(q0[0], q0[1]); xh[1] = pk2(q0[2], q0[3]);
    xh[2] = pk2(q1[0], q1[1]); xh[3] = pk2(q1[2], q1[3]);
    xh[4] = pk2(q2[0], q2[1]); xh[5] = pk2(q2[2], q2[3]);
    xh[6] = pk2(q3[0], q3[1]); xh[7] = pk2(q3[2], q3[3]);

    qptr += step2;
    if (t + 2*nwaves < ntiles) {   // wave-uniform prefetch, 2 iters ahead
      q0 = *(const float4v*)(qptr);      q1 = *(const float4v*)(qptr + 16);
      q2 = *(const float4v*)(qptr + 32); q3 = *(const float4v*)(qptr + 48);
    }

    // second factors for this lane half: xs[j] = xh[4h + j]
    f16x2 xs[4];
    #pragma unroll
    for (int j = 0; j < 4; ++j) xs[j] = sel2(lo, xh[j], xh[4+j]);

    f32x16 acc;
    #pragma unroll
    for (int r = 0; r < 16; ++r) acc[r] = 0.f;

    #pragma unroll
    for (int c = 0; c < 16; ++c) {
      _Float16 xi = xh[c >> 1][c & 1];
      H8 b;
      #pragma unroll
      for (int j = 0; j < 4; ++j) b.h2[j] = xs[j] * xi;  // v_pk_mul_f16
      acc = __builtin_amdgcn_mfma_f32_32x32x16_f16(Wf[c], b.h8, acc, 0, 0, 0);
    }
    {   // linear chunk
      H8 b;
      #pragma unroll
      for (int j = 0; j < 4; ++j) b.h2[j] = xs[j];
      acc = __builtin_amdgcn_mfma_f32_32x32x16_f16(Wf[16], b.h8, acc, 0, 0, 0);
    }
    // c2 chunk
    acc = __builtin_amdgcn_mfma_f32_32x32x16_f16(Wf[17], bC.h8, acc, 0, 0, 0);

    // epilogue: logsumexp (log2 domain), acc already includes c2
    float m = acc[0];
    #pragma unroll
    for (int r = 1; r < 16; ++r) m = fmaxf(m, acc[r]);
    m = fmaxf(m, partner32(m, lo));
    float s = 0.f;
    #pragma unroll
    for (int r = 0; r < 16; ++r) s += EXP2F(acc[r] - m);
    s += partner32(s, lo);
    accsum += m + LOG2F(s);
  };

  if (gwave < ntiles) {
    int t = gwave;
    for (;;) {
      body(pA0, pA1, pA2, pA3, ptrA, t);
      t += nwaves; if (t >= ntiles) break;
      body(pB0, pB1, pB2, pB3, ptrB, t);
      t += nwaves; if (t >= ntiles) break;
    }
  }

  #pragma unroll
  for (int off = 1; off <= 32; off <<= 1)
    accsum += __shfl_xor(accsum, off, 64);

  __shared__ float wsum[4];
  __shared__ int isLast;
  const int wid = (int)(threadIdx.x >> 6);
  if ((threadIdx.x & 63) == 0) wsum[wid] = accsum;
  __syncthreads();
  if (threadIdx.x == 0) {
    partials[blockIdx.x] = wsum[0] + wsum[1] + wsum[2] + wsum[3];
    __threadfence();                       // release partials (device scope)
    unsigned old = atomicAdd(counter, 1u); // device-scope ticket
    isLast = (old == gridDim.x - 1) ? 1 : 0;
  }
  __syncthreads();

  if (isLast) {
    __threadfence();                       // acquire all partials
    __shared__ double sd[256];
    double a = 0.0;
    for (int idx = (int)threadIdx.x; idx < (int)gridDim.x; idx += 256)
      a += (double)partials[idx];
    sd[threadIdx.x] = a;
    __syncthreads();
    for (int s = 128; s > 0; s >>= 1) {
      if ((int)threadIdx.x < s) sd[threadIdx.x] += sd[threadIdx.x + s];
      __syncthreads();
    }
    if (threadIdx.x == 0) out[0] = (float)(sd[0] * scale);
  }
}

// ---------------------------------------------------------------------------
extern "C" void kernel_launch(void* const* d_in, const int* in_sizes, int n_in,
                              void* d_out, int out_size, void* d_ws, size_t ws_size,
                              hipStream_t stream)
{
  const float* data        = (const float*)d_in[0];
  const float* means       = (const float*)d_in[1];
  const float* cov_parts   = (const float*)d_in[2];
  const float* log_weights = (const float*)d_in[3];

  const int npts   = in_sizes[0] / 16;
  const int ntiles = npts / 32;        // N = 2,000,000 divisible by 32

  _Float16* W        = (_Float16*)d_ws;                         // 18*64*8 halfs
  float*    partials = (float*)((char*)d_ws + 18432);           // 768 floats
  unsigned* counter  = (unsigned*)((char*)d_ws + 18432 + 3072); // 1 u32

  const int GRID = 768, BLOCK = 256;   // 3 blocks/CU, one resident round
  setup_kernel<<<32, 64, 0, stream>>>(means, cov_parts, log_weights, W, counter);
  main_kernel<<<GRID, BLOCK, 0, stream>>>(data, W, partials, counter,
                                          (float*)d_out,
                                          LN2_D / (2.0 * (double)npts), ntiles);
}

// Round 3
// 210.142 us; speedup vs baseline: 1.1153x; 1.1153x over previous
//
#include <hip/hip_runtime.h>
#include <math.h>

// ---------------------------------------------------------------------------
// GMM log-likelihood, N=2M x D=16, K=32, out = mean_n logsumexp_k loglik[n,k]
//
// loglik[n,k] = sum_{ij} (-0.5 P_ij) x_i x_j + (P mu)_i x_i + c_k  (log2 dom.)
// LINEAR in phi(x) = [ x_i*x_j (256), x_i (16), 1 ] -> 18 K16-chunks of one
// chained mfma_f32_32x32x16_f16 (M=32 = all comps; c_k folded in as chunk 17).
// C layout (HW-verified): col=lane&31 (point), row=(reg&3)+8*(reg>>2)+4*(lane>>5).
// Lane pair (l, l^32) holds all 32 comps of a point; combined via
// v_permlane32_swap (VALU-only; ds shuffles cost ~62 cyc each, R2).
//
// R9: R8 showed main ~87us with 1.5 serialized rounds ((256,3) not honored:
// occupancy 25.6% = 2 blocks/CU); back-solved R6/R7 main ~50us, insensitive
// to occupancy 8->12 waves/CU -> per-CU shared bottleneck: the stride-64
// gather (each dwordx4 touches 32 lines at 16B/lane = 128 L1 line-transactions
// per tile vs 32 coalesced; L1 is per-CU -> occupancy can't hide it).
// Fix: 2 perfectly-coalesced dwordx4 per tile + per-wave LDS transpose with
// XOR swizzle (p*64+j*16)^((p&7)<<4) — bijective, exactly 4 chunks/bank-quad
// -> conflict-free b128 writes AND reads. Double-buffered LDS + alternating
// reg sets: every dep >=1 iter of slack, no barriers (wave-private), no
// inline asm (compiler tracks reg->ds deps). Grid 512/(256,2) known-resident.
// Dual accumulators halve the 18-deep MFMA dependent chain (merge = 16 adds).
// Predict: main ~30us, total ~180 (147us poison-fills are harness-fixed).
// ---------------------------------------------------------------------------

#define LOG_2PI 1.8378770664093453f
#define INV_LN2 1.4426950408889634f
#define LN2_D   0.6931471805599453

typedef float    float4v __attribute__((ext_vector_type(4)));
typedef float    f32x16  __attribute__((ext_vector_type(16)));
typedef _Float16 f16x8   __attribute__((ext_vector_type(8)));
typedef _Float16 f16x2   __attribute__((ext_vector_type(2)));

union H8 { f16x8 h8; f16x2 h2[4]; };

#if __has_builtin(__builtin_amdgcn_exp2f)
#define EXP2F(x) __builtin_amdgcn_exp2f(x)
#else
#define EXP2F(x) exp2f(x)
#endif
#if __has_builtin(__builtin_amdgcn_logf)
#define LOG2F(x) __builtin_amdgcn_logf(x)
#else
#define LOG2F(x) log2f(x)
#endif

static __device__ __forceinline__ f16x2 pk2(float a, float b) {
#if __has_builtin(__builtin_amdgcn_cvt_pkrtz)
  return __builtin_bit_cast(f16x2, __builtin_amdgcn_cvt_pkrtz(a, b));
#else
  f16x2 r; r[0] = (_Float16)a; r[1] = (_Float16)b; return r;
#endif
}

// value of x in partner lane (lane ^ 32), VALU-only on gfx950
static __device__ __forceinline__ float partner32(float x, bool lo) {
#if __has_builtin(__builtin_amdgcn_permlane32_swap)
  typedef unsigned u32x2 __attribute__((ext_vector_type(2)));
  unsigned u = __builtin_bit_cast(unsigned, x);
  u32x2 r = __builtin_amdgcn_permlane32_swap(u, u, false, false);
  return __builtin_bit_cast(float, lo ? r[1] : r[0]);
#else
  return __shfl_xor(x, 32, 64);
#endif
}

// dword select (works for f16x2 payloads)
static __device__ __forceinline__ f16x2 sel2(bool c, f16x2 a, f16x2 b) {
  unsigned ua = __builtin_bit_cast(unsigned, a);
  unsigned ub = __builtin_bit_cast(unsigned, b);
  return __builtin_bit_cast(f16x2, c ? ua : ub);
}

// ---------------------------------------------------------------------------
// Setup: per component k: cov = A A^T, Cholesky L, Linv, P = Linv^T Linv.
// W in 32x32x16 A-frag order: lane l holds A[m=l&31][k16 = 8*(l>>5)+v],
// chunk c covers feature k = 16c + 8h + v.
// chunks 0..15: (i,j)=(c, 8h+v) -> -0.5/ln2 * P[i][j]
// chunk 16: linear, feature i=8h+v -> (P mu)_i / ln2
// chunk 17: constant, slot (h=0,v=0) -> c2[m]; all other slots 0
// Also zeroes the main-kernel's ticket counter each launch (graph replay).
// ---------------------------------------------------------------------------
__global__ void setup_kernel(const float* __restrict__ means,
                             const float* __restrict__ cov_parts,
                             const float* __restrict__ log_weights,
                             _Float16* __restrict__ W,
                             unsigned* __restrict__ counter)
{
  const int k = blockIdx.x;
  const int i = threadIdx.x;

  if (k == 0 && i == 0) counter[0] = 0u;

  __shared__ float sA[16][17];
  __shared__ float sC[16][17];
  __shared__ float sMu[16];
  __shared__ float sR[16];

  if (i < 16) {
    #pragma unroll
    for (int j = 0; j < 16; ++j) sA[i][j] = cov_parts[(k*16 + i)*16 + j];
    sMu[i] = means[k*16 + i];
  }
  __syncthreads();

  if (i < 16) {
    #pragma unroll
    for (int j = 0; j < 16; ++j) {
      float acc = 0.f;
      #pragma unroll
      for (int l = 0; l < 16; ++l) acc += sA[i][l] * sA[j][l];
      sC[i][j] = acc;
    }
  }
  __syncthreads();

  for (int j = 0; j < 16; ++j) {
    if (i == j) {
      float d = sC[j][j];
      for (int l = 0; l < j; ++l) d -= sC[j][l]*sC[j][l];
      sC[j][j] = sqrtf(d);
    }
    __syncthreads();
    if (i < 16 && i > j) {
      float a = sC[i][j];
      for (int l = 0; l < j; ++l) a -= sC[i][l]*sC[j][l];
      sC[i][j] = a / sC[j][j];
    }
    __syncthreads();
  }

  if (i < 16) {
    float y[16];
    #pragma unroll
    for (int r = 0; r < 16; ++r) {
      float a = (r == i) ? 1.f : 0.f;
      #pragma unroll
      for (int l = 0; l < r; ++l) a -= sC[r][l] * y[l];
      y[r] = a / sC[r][r];
    }
    #pragma unroll
    for (int r = 0; r < 16; ++r) sA[r][i] = y[r];
  }
  __syncthreads();

  if (i < 16) {
    float p[16];
    #pragma unroll
    for (int j = 0; j < 16; ++j) {
      float acc = 0.f;
      #pragma unroll
      for (int l = 0; l < 16; ++l) acc += sA[l][i] * sA[l][j];
      p[j] = acc;
    }
    float ri = 0.f;
    #pragma unroll
    for (int j = 0; j < 16; ++j) ri += p[j] * sMu[j];
    sR[i] = ri;

    #pragma unroll
    for (int j = 0; j < 16; ++j) {
      W[(size_t)(i*64 + (k + 32*(j >> 3)))*8 + (j & 7)] =
          (_Float16)(-0.5f * INV_LN2 * p[j]);
    }
    W[(size_t)(16*64 + (k + 32*(i >> 3)))*8 + (i & 7)] =
        (_Float16)(INV_LN2 * ri);
  }
  __syncthreads();

  if (i == 0) {
    float logdet = 0.f;
    #pragma unroll
    for (int j = 0; j < 16; ++j) logdet += __logf(sC[j][j]);
    float mupmu = 0.f;
    #pragma unroll
    for (int j = 0; j < 16; ++j) mupmu += sMu[j] * sR[j];
    float lw = log_weights[k];
    float c2v = INV_LN2 * (-0.5f*(mupmu + 16.f*LOG_2PI) - logdet + lw*lw);
    #pragma unroll
    for (int v = 0; v < 8; ++v) {
      W[(size_t)(17*64 + k)*8 + v]      = (v == 0) ? (_Float16)c2v : (_Float16)0.f;
      W[(size_t)(17*64 + k + 32)*8 + v] = (_Float16)0.f;
    }
  }
}

// ---------------------------------------------------------------------------
__global__ __launch_bounds__(256, 2) void main_kernel(
    const float* __restrict__ data,
    const _Float16* __restrict__ W,
    float* __restrict__ partials,
    unsigned* __restrict__ counter,
    float* __restrict__ out,
    double scale,
    int ntiles)
{
  const int tid  = (int)threadIdx.x;
  const int lane = tid & 63;
  const int n32  = lane & 31;
  const bool lo  = lane < 32;
  const int wid  = tid >> 6;
  const int gwave  = (int)((blockIdx.x * blockDim.x + tid) >> 6);
  const int nwaves = (int)((gridDim.x * blockDim.x) >> 6);

  // per-wave double-buffered staging: 4 waves x 2 bufs x 2048 B = 16 KB
  __shared__ __align__(16) char lds[4][2][2048];
  char* Lb0 = &lds[wid][0][0];
  char* Lb1 = &lds[wid][1][0];

  // lane-constant swizzled LDS addresses: chunk (p,j) lives at
  // (p*64 + j*16) ^ ((p&7)<<4)  — bijective, 4 chunks per bank-quad.
  const int pw0 = lane >> 2, jw = lane & 3;
  const int pw1 = 16 + pw0;
  const int wo0 = (pw0*64 + jw*16) ^ ((pw0 & 7) << 4);
  const int wo1 = (pw1*64 + jw*16) ^ ((pw1 & 7) << 4);
  const int rx  = (n32 & 7) << 4;
  const int ro0 = (n32*64 +  0) ^ rx;
  const int ro1 = (n32*64 + 16) ^ rx;
  const int ro2 = (n32*64 + 32) ^ rx;
  const int ro3 = (n32*64 + 48) ^ rx;

  // W fragments resident in registers for the whole kernel (72 regs)
  f16x8 Wf[18];
  #pragma unroll
  for (int c = 0; c < 18; ++c)
    Wf[c] = *(const f16x8*)(W + (size_t)(c*64 + lane)*8);

  // constant B fragment for the c2 chunk: slot (h=0,v=0) = 1
  H8 bC;
  #pragma unroll
  for (int j = 0; j < 4; ++j) bC.h2[j] = pk2(0.f, 0.f);
  if (lo) bC.h2[0] = pk2(1.f, 0.f);

  float accsum = 0.f;

  const char* base = (const char*)data;
  auto gload = [&](float4v& a, float4v& b, int t) {
    const char* p = base + (size_t)t*2048 + (size_t)lane*16;
    a = *(const float4v*)(p);
    b = *(const float4v*)(p + 1024);
  };

  // compute one 32-point tile from staged LDS buffer Lr
  auto compute = [&](const char* Lr) {
    float4v r0 = *(const float4v*)(Lr + ro0);
    float4v r1 = *(const float4v*)(Lr + ro1);
    float4v r2 = *(const float4v*)(Lr + ro2);
    float4v r3 = *(const float4v*)(Lr + ro3);

    f16x2 xh[8];
    xh[0] = pk2(r0[0], r0[1]); xh[1] = pk2(r0[2], r0[3]);
    xh[2] = pk2(r1[0], r1[1]); xh[3] = pk2(r1[2], r1[3]);
    xh[4] = pk2(r2[0], r2[1]); xh[5] = pk2(r2[2], r2[3]);
    xh[6] = pk2(r3[0], r3[1]); xh[7] = pk2(r3[2], r3[3]);

    f16x2 xs[4];
    #pragma unroll
    for (int j = 0; j < 4; ++j) xs[j] = sel2(lo, xh[j], xh[4+j]);

    f32x16 acc0, acc1;
    #pragma unroll
    for (int r = 0; r < 16; ++r) { acc0[r] = 0.f; acc1[r] = 0.f; }

    #pragma unroll
    for (int c = 0; c < 16; ++c) {
      _Float16 xi = xh[c >> 1][c & 1];
      H8 b;
      #pragma unroll
      for (int j = 0; j < 4; ++j) b.h2[j] = xs[j] * xi;  // v_pk_mul_f16
      if (c & 1)
        acc1 = __builtin_amdgcn_mfma_f32_32x32x16_f16(Wf[c], b.h8, acc1, 0, 0, 0);
      else
        acc0 = __builtin_amdgcn_mfma_f32_32x32x16_f16(Wf[c], b.h8, acc0, 0, 0, 0);
    }
    {   // linear chunk -> acc1
      H8 b;
      #pragma unroll
      for (int j = 0; j < 4; ++j) b.h2[j] = xs[j];
      acc1 = __builtin_amdgcn_mfma_f32_32x32x16_f16(Wf[16], b.h8, acc1, 0, 0, 0);
    }
    // c2 chunk -> acc0
    acc0 = __builtin_amdgcn_mfma_f32_32x32x16_f16(Wf[17], bC.h8, acc0, 0, 0, 0);

    f32x16 acc = acc0 + acc1;

    // epilogue: logsumexp (log2 domain), acc already includes c2
    float m = acc[0];
    #pragma unroll
    for (int r = 1; r < 16; ++r) m = fmaxf(m, acc[r]);
    m = fmaxf(m, partner32(m, lo));
    float s = 0.f;
    #pragma unroll
    for (int r = 0; r < 16; ++r) s += EXP2F(acc[r] - m);
    s += partner32(s, lo);
    accsum += m + LOG2F(s);
  };

  // prologue: stage tile t0 into buf0; preload tile t0+nw into B regs
  float4v A0, A1, B0, B1;
  const int t0 = gwave;
  if (t0 < ntiles) gload(A0, A1, t0);
  if (t0 + nwaves < ntiles) gload(B0, B1, t0 + nwaves);
  if (t0 < ntiles) {
    *(float4v*)(Lb0 + wo0) = A0;
    *(float4v*)(Lb0 + wo1) = A1;
  }

  // steady state, unrolled x2 (alternating reg sets + LDS buffers):
  //   body(t even-local): write B(t+nw)->buf1, load A<-t+2nw, compute buf0
  //   body(t odd-local) : write A(t+nw)->buf0, load B<-t+2nw, compute buf1
  // Every dependency (global->ds_write, ds_write->ds_read, WAR on regs)
  // has >= 1 full body of slack; LDS ops are wave-private and in-order.
  if (t0 < ntiles) {
    int t = t0;
    for (;;) {
      if (t + nwaves < ntiles) {
        *(float4v*)(Lb1 + wo0) = B0;
        *(float4v*)(Lb1 + wo1) = B1;
      }
      if (t + 2*nwaves < ntiles) gload(A0, A1, t + 2*nwaves);
      compute(Lb0);
      t += nwaves; if (t >= ntiles) break;

      if (t + nwaves < ntiles) {
        *(float4v*)(Lb0 + wo0) = A0;
        *(float4v*)(Lb0 + wo1) = A1;
      }
      if (t + 2*nwaves < ntiles) gload(B0, B1, t + 2*nwaves);
      compute(Lb1);
      t += nwaves; if (t >= ntiles) break;
    }
  }

  #pragma unroll
  for (int off = 1; off <= 32; off <<= 1)
    accsum += __shfl_xor(accsum, off, 64);

  __shared__ float wsum[4];
  __shared__ int isLast;
  if ((tid & 63) == 0) wsum[wid] = accsum;
  __syncthreads();
  if (tid == 0) {
    partials[blockIdx.x] = wsum[0] + wsum[1] + wsum[2] + wsum[3];
    __threadfence();                       // release partials (device scope)
    unsigned old = atomicAdd(counter, 1u); // device-scope ticket
    isLast = (old == gridDim.x - 1) ? 1 : 0;
  }
  __syncthreads();

  if (isLast) {
    __threadfence();                       // acquire all partials
    __shared__ double sd[256];
    double a = 0.0;
    for (int idx = tid; idx < (int)gridDim.x; idx += 256)
      a += (double)partials[idx];
    sd[tid] = a;
    __syncthreads();
    for (int s = 128; s > 0; s >>= 1) {
      if (tid < s) sd[tid] += sd[tid + s];
      __syncthreads();
    }
    if (tid == 0) out[0] = (float)(sd[0] * scale);
  }
}

// ---------------------------------------------------------------------------
extern "C" void kernel_launch(void* const* d_in, const int* in_sizes, int n_in,
                              void* d_out, int out_size, void* d_ws, size_t ws_size,
                              hipStream_t stream)
{
  const float* data        = (const float*)d_in[0];
  const float* means       = (const float*)d_in[1];
  const float* cov_parts   = (const float*)d_in[2];
  const float* log_weights = (const float*)d_in[3];

  const int npts   = in_sizes[0] / 16;
  const int ntiles = npts / 32;        // N = 2,000,000 divisible by 32

  _Float16* W        = (_Float16*)d_ws;                         // 18*64*8 halfs
  float*    partials = (float*)((char*)d_ws + 18432);           // 512 floats
  unsigned* counter  = (unsigned*)((char*)d_ws + 18432 + 3072); // 1 u32

  const int GRID = 512, BLOCK = 256;   // 2 blocks/CU, known-resident (R6)
  setup_kernel<<<32, 64, 0, stream>>>(means, cov_parts, log_weights, W, counter);
  main_kernel<<<GRID, BLOCK, 0, stream>>>(data, W, partials, counter,
                                          (float*)d_out,
                                          LN2_D / (2.0 * (double)npts), ntiles);
}